// Round 6
// baseline (236.913 us; speedup 1.0000x reference)
//
#include <hip/hip_runtime.h>

// Problem constants (fixed by reference setup_inputs)
#define B_    8
#define C_    16
#define T_    2000
#define F_    128
#define F4_   32           // float4 per full feature row
#define POOL_ 10
#define T1_   200          // T_/POOL_ (exact, no tail)
#define BC_   128          // B_*C_
#define EPS_  1e-5f

#define NG_   50           // groups of 4 pooled blocks (40 rows) per scan
#define GS_   (40 * F4_)   // group stride in float4 (1280)
#define RSR_  (2 * F4_)    // same-parity row stride in float4 (64)

// ---------------------------------------------------------------------------
// Barrier-free, LDS-free fused causal instance-norm.
// Rounds 2-5 post-mortem: occupancy, vmcnt-free barriers, and register
// prefetch were ALL null/negative -> the WG barrier phase-locks load issue
// into bursts (avg ~2 KB in flight/CU vs ~9 KB Little's-law target), and
// sched_barrier fences block the compiler from pipelining across it.
// New structure: ONE WAVE owns one (bc, feature-quarter) scan. Lane
// (j = l>>4, h = (l>>3)&1, f4 = l&7) processes the 5 parity-h rows of pooled
// block j in each group of 4 blocks -> each lane's rows live in exactly one
// block. Per group: h-fold (shfl_xor 8), 2-stage Kogge-Stone inclusive
// prefix across the 4 j-clusters, broadcast cluster-3 total into the
// register-resident running sums, stats, normalize held regs, store.
// Zero s_barrier / LDS / sched_barrier: compiler pipelines freely. Named
// A/B/C register sets give distance-2 prefetch with static indices.
// x read once (131 MB), out written once (131 MB).
// ---------------------------------------------------------------------------

// 2-stage Kogge-Stone inclusive prefix across the 4 16-lane clusters.
// Values are uniform within a cluster; sources are (lane-16) and (lane-32).
#define PFX(av)                                                               \
    { float t1_ = __shfl((av), lm16); (av) += jge1 ? t1_ : 0.0f;              \
      float t2_ = __shfl((av), lm32); (av) += jge2 ? t2_ : 0.0f; }

#define STEP(kk, V0,V1,V2,V3,V4, P0,P1,P2,P3,P4)                              \
  {                                                                           \
    /* prefetch group kk+2 into P* (clamped reload of g0 at tail: free) */    \
    int kpf_ = (kk) + 2; if (kpf_ >= NG_) kpf_ = 0;                           \
    const float4* pp_ = pbase + (size_t)kpf_ * GS_;                           \
    P0 = pp_[0]; P1 = pp_[RSR_]; P2 = pp_[2*RSR_];                            \
    P3 = pp_[3*RSR_]; P4 = pp_[4*RSR_];                                       \
    /* partial sums of this lane's 5 rows (all in pooled block j) */          \
    float4 s_, s2_;                                                           \
    s_.x = ((V0.x+V1.x)+(V2.x+V3.x))+V4.x;                                    \
    s_.y = ((V0.y+V1.y)+(V2.y+V3.y))+V4.y;                                    \
    s_.z = ((V0.z+V1.z)+(V2.z+V3.z))+V4.z;                                    \
    s_.w = ((V0.w+V1.w)+(V2.w+V3.w))+V4.w;                                    \
    s2_.x = V0.x*V0.x; s2_.x = fmaf(V1.x,V1.x,s2_.x); s2_.x = fmaf(V2.x,V2.x,s2_.x); s2_.x = fmaf(V3.x,V3.x,s2_.x); s2_.x = fmaf(V4.x,V4.x,s2_.x); \
    s2_.y = V0.y*V0.y; s2_.y = fmaf(V1.y,V1.y,s2_.y); s2_.y = fmaf(V2.y,V2.y,s2_.y); s2_.y = fmaf(V3.y,V3.y,s2_.y); s2_.y = fmaf(V4.y,V4.y,s2_.y); \
    s2_.z = V0.z*V0.z; s2_.z = fmaf(V1.z,V1.z,s2_.z); s2_.z = fmaf(V2.z,V2.z,s2_.z); s2_.z = fmaf(V3.z,V3.z,s2_.z); s2_.z = fmaf(V4.z,V4.z,s2_.z); \
    s2_.w = V0.w*V0.w; s2_.w = fmaf(V1.w,V1.w,s2_.w); s2_.w = fmaf(V2.w,V2.w,s2_.w); s2_.w = fmaf(V3.w,V3.w,s2_.w); s2_.w = fmaf(V4.w,V4.w,s2_.w); \
    /* fold h-pair: lanes l <-> l^8 -> per-block sums, uniform in h */        \
    s_.x  += __shfl_xor(s_.x , 8); s_.y  += __shfl_xor(s_.y , 8);             \
    s_.z  += __shfl_xor(s_.z , 8); s_.w  += __shfl_xor(s_.w , 8);             \
    s2_.x += __shfl_xor(s2_.x, 8); s2_.y += __shfl_xor(s2_.y, 8);             \
    s2_.z += __shfl_xor(s2_.z, 8); s2_.w += __shfl_xor(s2_.w, 8);             \
    /* inclusive prefix over j-clusters */                                    \
    float4 a_ = s_, a2_ = s2_;                                                \
    PFX(a_.x); PFX(a_.y); PFX(a_.z); PFX(a_.w);                               \
    PFX(a2_.x); PFX(a2_.y); PFX(a2_.z); PFX(a2_.w);                           \
    /* causal totals for this lane's block; update running sums (uniform) */  \
    float4 ct_, ct2_;                                                         \
    ct_.x  = rs.x  + a_.x;  ct_.y  = rs.y  + a_.y;                            \
    ct_.z  = rs.z  + a_.z;  ct_.w  = rs.w  + a_.w;                            \
    ct2_.x = rs2.x + a2_.x; ct2_.y = rs2.y + a2_.y;                           \
    ct2_.z = rs2.z + a2_.z; ct2_.w = rs2.w + a2_.w;                           \
    rs.x  += __shfl(a_.x,  lbc); rs.y  += __shfl(a_.y,  lbc);                 \
    rs.z  += __shfl(a_.z,  lbc); rs.w  += __shfl(a_.w,  lbc);                 \
    rs2.x += __shfl(a2_.x, lbc); rs2.y += __shfl(a2_.y, lbc);                 \
    rs2.z += __shfl(a2_.z, lbc); rs2.w += __shfl(a2_.w, lbc);                 \
    /* stats: n = (#blocks)*POOL elements */                                  \
    const float inv_ = 1.0f / (float)((((kk) << 2) + j + 1) * POOL_);         \
    float4 mean_, rstd_;                                                      \
    mean_.x = ct_.x * inv_; rstd_.x = rsqrtf(fmaf(-mean_.x, mean_.x, ct2_.x * inv_) + EPS_); \
    mean_.y = ct_.y * inv_; rstd_.y = rsqrtf(fmaf(-mean_.y, mean_.y, ct2_.y * inv_) + EPS_); \
    mean_.z = ct_.z * inv_; rstd_.z = rsqrtf(fmaf(-mean_.z, mean_.z, ct2_.z * inv_) + EPS_); \
    mean_.w = ct_.w * inv_; rstd_.w = rsqrtf(fmaf(-mean_.w, mean_.w, ct2_.w * inv_) + EPS_); \
    /* normalize held registers, store */                                     \
    float4* qq_ = qbase + (size_t)(kk) * GS_;                                 \
    float4 o_;                                                                \
    o_.x=(V0.x-mean_.x)*rstd_.x; o_.y=(V0.y-mean_.y)*rstd_.y;                 \
    o_.z=(V0.z-mean_.z)*rstd_.z; o_.w=(V0.w-mean_.w)*rstd_.w; qq_[0]      = o_; \
    o_.x=(V1.x-mean_.x)*rstd_.x; o_.y=(V1.y-mean_.y)*rstd_.y;                 \
    o_.z=(V1.z-mean_.z)*rstd_.z; o_.w=(V1.w-mean_.w)*rstd_.w; qq_[RSR_]   = o_; \
    o_.x=(V2.x-mean_.x)*rstd_.x; o_.y=(V2.y-mean_.y)*rstd_.y;                 \
    o_.z=(V2.z-mean_.z)*rstd_.z; o_.w=(V2.w-mean_.w)*rstd_.w; qq_[2*RSR_] = o_; \
    o_.x=(V3.x-mean_.x)*rstd_.x; o_.y=(V3.y-mean_.y)*rstd_.y;                 \
    o_.z=(V3.z-mean_.z)*rstd_.z; o_.w=(V3.w-mean_.w)*rstd_.w; qq_[3*RSR_] = o_; \
    o_.x=(V4.x-mean_.x)*rstd_.x; o_.y=(V4.y-mean_.y)*rstd_.y;                 \
    o_.z=(V4.z-mean_.z)*rstd_.z; o_.w=(V4.w-mean_.w)*rstd_.w; qq_[4*RSR_] = o_; \
  }

__global__ __launch_bounds__(64) void fused_cumnorm_wave(
    const float4* __restrict__ x4, float4* __restrict__ out4)
{
    const int lane = (int)threadIdx.x;     // 0..63
    const int bc   = (int)blockIdx.x >> 2;
    const int q    = (int)blockIdx.x & 3;
    const int f4   = lane & 7;             // float4 column within quarter
    const int h    = (lane >> 3) & 1;      // row parity within block
    const int j    = lane >> 4;            // block within group (cluster)

    const int  lm16 = (lane - 16) & 63;    // prefix stage-1 source
    const int  lm32 = (lane - 32) & 63;    // prefix stage-2 source
    const int  lbc  = 48 | (lane & 15);    // cluster-3 broadcast source
    const bool jge1 = (j >= 1), jge2 = (j >= 2);

    const size_t base = (size_t)bc * (T_ * F4_)
                      + (size_t)(j * POOL_ + h) * F4_
                      + (size_t)(q * 8 + f4);
    const float4* __restrict__ pbase = x4   + base;
    float4*       __restrict__ qbase = out4 + base;

    float4 rs  = {0.f, 0.f, 0.f, 0.f};     // running sums (register-resident)
    float4 rs2 = {0.f, 0.f, 0.f, 0.f};

    // named register sets: distance-2 prefetch, all indices static (rule #20)
    float4 A0,A1,A2,A3,A4, B0,B1,B2,B3,B4, C0,C1,C2,C3,C4;
    { const float4* p = pbase;       A0=p[0]; A1=p[RSR_]; A2=p[2*RSR_]; A3=p[3*RSR_]; A4=p[4*RSR_]; }
    { const float4* p = pbase + GS_; B0=p[0]; B1=p[RSR_]; B2=p[2*RSR_]; B3=p[3*RSR_]; B4=p[4*RSR_]; }

    int k = 0;
#pragma unroll 1
    for (int it = 0; it < (NG_ - 2) / 3; ++it) {   // 16 iters -> k = 0..47
        STEP(k, A0,A1,A2,A3,A4, C0,C1,C2,C3,C4); ++k;
        STEP(k, B0,B1,B2,B3,B4, A0,A1,A2,A3,A4); ++k;
        STEP(k, C0,C1,C2,C3,C4, B0,B1,B2,B3,B4); ++k;
    }
    STEP(k, A0,A1,A2,A3,A4, C0,C1,C2,C3,C4); ++k;  // k = 48 (prefetch clamps)
    STEP(k, B0,B1,B2,B3,B4, A0,A1,A2,A3,A4);       // k = 49 (prefetch clamps)
}

extern "C" void kernel_launch(void* const* d_in, const int* in_sizes, int n_in,
                              void* d_out, int out_size, void* d_ws, size_t ws_size,
                              hipStream_t stream)
{
    (void)in_sizes; (void)n_in; (void)d_ws; (void)ws_size; (void)out_size;
    // 512 single-wave workgroups (128 bc x 4 feature-quarters) = 2 waves/CU.
    // No barriers / LDS: occupancy counter will read ~6% -- intentional.
    fused_cumnorm_wave<<<BC_ * 4, 64, 0, stream>>>(
        (const float4*)d_in[0], (float4*)d_out);
}